// Round 1
// baseline (389.289 us; speedup 1.0000x reference)
//
#include <hip/hip_runtime.h>

// B=2, T=2048, C=1024, H=16, hd=64, LOCAL_WINDOW=512, MAX_REL_DIST=128
#define T_SEQ 2048
#define HD 64

typedef float f32x4 __attribute__((ext_vector_type(4)));
typedef __bf16 bf16x8 __attribute__((ext_vector_type(8)));
typedef unsigned short ushort4v __attribute__((ext_vector_type(4)));
typedef unsigned short ushort8v __attribute__((ext_vector_type(8)));

__device__ __forceinline__ unsigned short f2bf(float f) {
    unsigned u = __builtin_bit_cast(unsigned, f);
    u += 0x7fffu + ((u >> 16) & 1u);
    return (unsigned short)(u >> 16);
}

// out[n][m] = sum_k A[n][k] * W[m][k], K=1024.
// MODE 0: scatter into q/k/v (B,H,T,hd) layouts (o0,o1,o2).
// MODE 1: o0[n*1024+m] = val + bias[m].
template<int MODE>
__global__ __launch_bounds__(256)
void gemm_kernel(const float* __restrict__ A, const float* __restrict__ W,
                 float* __restrict__ o0, float* __restrict__ o1,
                 float* __restrict__ o2, const float* __restrict__ bias)
{
    constexpr int K = 1024;
    constexpr int LDA = 40;  // 32 bf16 + 8 pad (80B rows: keeps b128 16B-aligned, 2-way banks)
    __shared__ unsigned short As[128 * LDA];
    __shared__ unsigned short Bs[128 * LDA];
    const int t = threadIdx.x;
    const int m0 = blockIdx.x * 128;
    const int n0 = blockIdx.y * 128;
    const int lane = t & 63;
    const int wave = t >> 6;
    const int wy = wave >> 1, wx = wave & 1;
    const int l15 = lane & 15, quad = lane >> 4;

    f32x4 acc[4][4] = {};

    for (int kc = 0; kc < K; kc += 32) {
        // stage A,W tiles (fp32 -> bf16 fused)
#pragma unroll
        for (int i = 0; i < 4; ++i) {
            int li = t + i * 256;            // 0..1023
            int row = li >> 3, c = li & 7;   // 128 rows x 8 float4
            f32x4 av = *reinterpret_cast<const f32x4*>(A + (size_t)(n0 + row) * K + kc + c * 4);
            f32x4 wv = *reinterpret_cast<const f32x4*>(W + (size_t)(m0 + row) * K + kc + c * 4);
            ushort4v ac, wc;
#pragma unroll
            for (int j = 0; j < 4; ++j) { ac[j] = f2bf(av[j]); wc[j] = f2bf(wv[j]); }
            *reinterpret_cast<ushort4v*>(&As[row * LDA + c * 4]) = ac;
            *reinterpret_cast<ushort4v*>(&Bs[row * LDA + c * 4]) = wc;
        }
        __syncthreads();
        bf16x8 af[4], bfr[4];
#pragma unroll
        for (int nt = 0; nt < 4; ++nt)
            af[nt] = __builtin_bit_cast(bf16x8,
                *reinterpret_cast<const ushort8v*>(&As[(wy * 64 + nt * 16 + l15) * LDA + quad * 8]));
#pragma unroll
        for (int mt = 0; mt < 4; ++mt)
            bfr[mt] = __builtin_bit_cast(bf16x8,
                *reinterpret_cast<const ushort8v*>(&Bs[(wx * 64 + mt * 16 + l15) * LDA + quad * 8]));
#pragma unroll
        for (int nt = 0; nt < 4; ++nt)
#pragma unroll
            for (int mt = 0; mt < 4; ++mt)
                acc[nt][mt] = __builtin_amdgcn_mfma_f32_16x16x32_bf16(af[nt], bfr[mt], acc[nt][mt], 0, 0, 0);
        __syncthreads();
    }

    // epilogue: lane holds rows quad*4+r, col l15 of each 16x16 tile
#pragma unroll
    for (int nt = 0; nt < 4; ++nt) {
#pragma unroll
        for (int mt = 0; mt < 4; ++mt) {
            const int m = m0 + wx * 64 + mt * 16 + l15;
#pragma unroll
            for (int r = 0; r < 4; ++r) {
                const int n = n0 + wy * 64 + nt * 16 + quad * 4 + r;
                float val = acc[nt][mt][r];
                if (MODE == 0) {
                    int bb = n >> 11, tt = n & 2047;
                    int s = m >> 10, h = (m >> 6) & 15, d = m & 63;
                    float* dst = (s == 0) ? o0 : ((s == 1) ? o1 : o2);
                    dst[((size_t)((bb << 4) + h) * T_SEQ + tt) * HD + d] = val;
                } else {
                    o0[(size_t)n * 1024 + m] = val + bias[m];
                }
            }
        }
    }
}

// flash-style local attention, fp32. grid (T/64, B*H), block 256.
__global__ __launch_bounds__(256)
void attn_kernel(const float* __restrict__ qg, const float* __restrict__ kg,
                 const float* __restrict__ vg, const float* __restrict__ rel_bias,
                 float* __restrict__ y)
{
    __shared__ float Qs[64][65];   // odd pad: scalar reads conflict-free
    __shared__ float KV[64][68];   // holds K then V; pad 68 keeps float4 alignment
    __shared__ float Sm[64][65];
    __shared__ float bias_s[257];
    __shared__ float m_s[64], l_s[64], alpha_s[64];
    __shared__ float red[64][4];

    const int t = threadIdx.x;
    const int qt = blockIdx.x, bh = blockIdx.y;
    const int b = bh >> 4, h = bh & 15;
    const int q0 = qt << 6;
    const size_t base = (size_t)bh * T_SEQ * HD;

    // load Q tile
#pragma unroll
    for (int i = 0; i < 4; ++i) {
        int li = t + i * 256;
        int row = li >> 4, c4 = li & 15;
        f32x4 qv = *reinterpret_cast<const f32x4*>(qg + base + (size_t)(q0 + row) * HD + c4 * 4);
#pragma unroll
        for (int j = 0; j < 4; ++j) Qs[row][c4 * 4 + j] = qv[j];
    }
    for (int idx = t; idx < 257; idx += 256) bias_s[idx] = rel_bias[idx * 16 + h];
    if (t < 64) { m_s[t] = -1e30f; l_s[t] = 0.f; }

    const int r0 = (t & 15) * 4;   // S-compute & PV row group
    const int c0 = (t >> 4) * 4;   // S-compute col group / PV dim group
    f32x4 Oacc[4] = {};

    const int kt0 = (qt > 8) ? (qt - 8) : 0;
    __syncthreads();

    for (int kt = kt0; kt <= qt; ++kt) {
        // stage K tile
#pragma unroll
        for (int i = 0; i < 4; ++i) {
            int li = t + i * 256;
            int row = li >> 4, c4 = li & 15;
            f32x4 kv = *reinterpret_cast<const f32x4*>(kg + base + (size_t)(kt * 64 + row) * HD + c4 * 4);
            *reinterpret_cast<f32x4*>(&KV[row][c4 * 4]) = kv;
        }
        __syncthreads();
        // S = Q K^T (4x4 per thread), then scale+mask+bias
        {
            float sacc[4][4] = {};
            for (int d = 0; d < 64; ++d) {
                float qv[4], kv[4];
#pragma unroll
                for (int i = 0; i < 4; ++i) qv[i] = Qs[r0 + i][d];
#pragma unroll
                for (int j = 0; j < 4; ++j) kv[j] = KV[c0 + j][d];
#pragma unroll
                for (int i = 0; i < 4; ++i)
#pragma unroll
                    for (int j = 0; j < 4; ++j) sacc[i][j] += qv[i] * kv[j];
            }
#pragma unroll
            for (int i = 0; i < 4; ++i) {
                int ig = q0 + r0 + i;
#pragma unroll
                for (int j = 0; j < 4; ++j) {
                    int jg = (kt << 6) + c0 + j;
                    int diff = ig - jg;
                    float sv;
                    if (diff < 0 || diff > 512) sv = -1e30f;
                    else sv = sacc[i][j] * 0.125f + bias_s[(diff < 128 ? diff : 128) + 128];
                    Sm[r0 + i][c0 + j] = sv;
                }
            }
        }
        __syncthreads();
        // stage V (overwrites K) + per-row partial max
#pragma unroll
        for (int i = 0; i < 4; ++i) {
            int li = t + i * 256;
            int row = li >> 4, c4 = li & 15;
            f32x4 vv = *reinterpret_cast<const f32x4*>(vg + base + (size_t)(kt * 64 + row) * HD + c4 * 4);
            *reinterpret_cast<f32x4*>(&KV[row][c4 * 4]) = vv;
        }
        {
            int r = t & 63, qq = t >> 6;
            float pm = -1e30f;
            for (int c = qq * 16; c < qq * 16 + 16; ++c) pm = fmaxf(pm, Sm[r][c]);
            red[r][qq] = pm;
        }
        __syncthreads();
        if (t < 64) {
            float rowmax = fmaxf(fmaxf(red[t][0], red[t][1]), fmaxf(red[t][2], red[t][3]));
            float mold = m_s[t];
            float newm = fmaxf(mold, rowmax);
            m_s[t] = newm;
            alpha_s[t] = __expf(mold - newm);
        }
        __syncthreads();
        {
            int r = t & 63, qq = t >> 6;
            float newm = m_s[r], ps = 0.f;
            for (int c = qq * 16; c < qq * 16 + 16; ++c) {
                float p = __expf(Sm[r][c] - newm);
                Sm[r][c] = p;
                ps += p;
            }
            red[r][qq] = ps;
        }
        __syncthreads();
        if (t < 64)
            l_s[t] = l_s[t] * alpha_s[t] + red[t][0] + red[t][1] + red[t][2] + red[t][3];
        // O = O*alpha + P V   (thread: rows r0..r0+3, dims c0..c0+3)
        {
#pragma unroll
            for (int i = 0; i < 4; ++i) Oacc[i] *= alpha_s[r0 + i];
            for (int c = 0; c < 64; ++c) {
                f32x4 vv = *reinterpret_cast<f32x4*>(&KV[c][c0]);
#pragma unroll
                for (int i = 0; i < 4; ++i) Oacc[i] += Sm[r0 + i][c] * vv;
            }
        }
        __syncthreads();
    }
    // normalize + write (B,T,C) with head offset
#pragma unroll
    for (int i = 0; i < 4; ++i) {
        float inv = 1.0f / l_s[r0 + i];
        f32x4 ov = Oacc[i] * inv;
        *reinterpret_cast<f32x4*>(y + ((size_t)b * T_SEQ + q0 + r0 + i) * 1024 + h * HD + c0) = ov;
    }
}

extern "C" void kernel_launch(void* const* d_in, const int* in_sizes, int n_in,
                              void* d_out, int out_size, void* d_ws, size_t ws_size,
                              hipStream_t stream)
{
    (void)in_sizes; (void)n_in; (void)out_size; (void)ws_size;
    const float* x        = (const float*)d_in[0];
    const float* w_qkv    = (const float*)d_in[1];
    const float* w_proj   = (const float*)d_in[2];
    const float* b_proj   = (const float*)d_in[3];
    const float* rel_bias = (const float*)d_in[4];
    float* out = (float*)d_out;

    float* qf = (float*)d_ws;                 // 4 x 16MB fp32 scratch regions
    float* kf = qf + (size_t)4194304;
    float* vf = kf + (size_t)4194304;
    float* ya = vf + (size_t)4194304;

    // qkv projection: (4096x1024) @ (3072x1024)^T -> scatter q,k,v (B,H,T,hd)
    gemm_kernel<0><<<dim3(24, 32), 256, 0, stream>>>(x, w_qkv, qf, kf, vf, nullptr);
    // local attention -> ya (B,T,C)
    attn_kernel<<<dim3(32, 32), 256, 0, stream>>>(qf, kf, vf, rel_bias, ya);
    // output projection + bias -> out
    gemm_kernel<1><<<dim3(8, 32), 256, 0, stream>>>(ya, w_proj, out, nullptr, nullptr, b_proj);
}

// Round 3
// 187.925 us; speedup vs baseline: 2.0715x; 2.0715x over previous
//
#include <hip/hip_runtime.h>

// B=2, T=2048, C=1024, H=16, hd=64, LOCAL_WINDOW=512, MAX_REL_DIST=128
#define T_SEQ 2048
#define HD 64

typedef float f32x4 __attribute__((ext_vector_type(4)));
typedef __bf16 bf16x8 __attribute__((ext_vector_type(8)));
typedef unsigned short ushort8v __attribute__((ext_vector_type(8)));

__device__ __forceinline__ unsigned short f2bf(float f) {
    unsigned u = __builtin_bit_cast(unsigned, f);
    u += 0x7fffu + ((u >> 16) & 1u);
    return (unsigned short)(u >> 16);
}

__device__ __forceinline__ void gll16(const void* g, void* lds) {
    __builtin_amdgcn_global_load_lds(
        (const __attribute__((address_space(1))) unsigned int*)g,
        (__attribute__((address_space(3))) unsigned int*)lds, 16, 0, 0);
}

__device__ __forceinline__ bf16x8 ldfrag(const unsigned short* p) {
    return __builtin_bit_cast(bf16x8, *reinterpret_cast<const ushort8v*>(p));
}

// fp32 -> bf16 bulk convert, 8 elems/thread, n % 2048 == 0
__global__ __launch_bounds__(256)
void cvt_kernel(const float* __restrict__ s, unsigned short* __restrict__ d) {
    int i = (blockIdx.x * 256 + threadIdx.x) * 8;
    f32x4 a = *reinterpret_cast<const f32x4*>(s + i);
    f32x4 b = *reinterpret_cast<const f32x4*>(s + i + 4);
    ushort8v o;
#pragma unroll
    for (int j = 0; j < 4; ++j) { o[j] = f2bf(a[j]); o[4 + j] = f2bf(b[j]); }
    *reinterpret_cast<ushort8v*>(d + i) = o;
}

// out[n][m] = sum_k A[n][k]*W[m][k], K=1024, bf16 inputs, m97-style staging.
// MODE 0: scatter bf16 into q/k/v (B,H,T,hd). MODE 1: o0[n*1024+m]=val+bias[m] fp32.
template<int MODE>
__global__ __launch_bounds__(256)
void gemm_kernel(const unsigned short* __restrict__ A, const unsigned short* __restrict__ W,
                 float* __restrict__ o0, unsigned short* __restrict__ qo,
                 unsigned short* __restrict__ ko, unsigned short* __restrict__ vo,
                 const float* __restrict__ bias)
{
    constexpr int K = 1024;
    __shared__ unsigned short As[128 * 32];   // unpadded: required by global_load_lds
    __shared__ unsigned short Bs[128 * 32];
    const int t = threadIdx.x;
    const int m0 = blockIdx.x * 128, n0 = blockIdx.y * 128;
    const int lane = t & 63, w = t >> 6;
    const int wy = w >> 1, wx = w & 1;
    const int l15 = lane & 15, quad = lane >> 4;

    f32x4 acc[4][4] = {};
    const char* Ab = (const char*)A;
    const char* Wb = (const char*)W;

    for (int kc = 0; kc < K; kc += 32) {
#pragma unroll
        for (int i = 0; i < 2; ++i) {
            int c = w * 2 + i;                  // chunk 0..7 (1 KB each)
            int lin = c * 1024 + lane * 16;     // byte within 8KB tile
            int row = lin >> 6, colb = lin & 63;
            gll16(Ab + ((size_t)(n0 + row) * K + kc) * 2 + colb, (char*)As + c * 1024);
            gll16(Wb + ((size_t)(m0 + row) * K + kc) * 2 + colb, (char*)Bs + c * 1024);
        }
        __syncthreads();
        bf16x8 af[4], bfr[4];
#pragma unroll
        for (int nt = 0; nt < 4; ++nt)
            af[nt] = ldfrag(As + (wy * 64 + nt * 16 + l15) * 32 + quad * 8);
#pragma unroll
        for (int mt = 0; mt < 4; ++mt)
            bfr[mt] = ldfrag(Bs + (wx * 64 + mt * 16 + l15) * 32 + quad * 8);
#pragma unroll
        for (int nt = 0; nt < 4; ++nt)
#pragma unroll
            for (int mt = 0; mt < 4; ++mt)
                acc[nt][mt] = __builtin_amdgcn_mfma_f32_16x16x32_bf16(af[nt], bfr[mt], acc[nt][mt], 0, 0, 0);
        __syncthreads();
    }

#pragma unroll
    for (int nt = 0; nt < 4; ++nt) {
#pragma unroll
        for (int mt = 0; mt < 4; ++mt) {
            const int m = m0 + wx * 64 + mt * 16 + l15;
#pragma unroll
            for (int r = 0; r < 4; ++r) {
                const int n = n0 + wy * 64 + nt * 16 + quad * 4 + r;
                float val = acc[nt][mt][r];
                if (MODE == 0) {
                    int bb = n >> 11, tt = n & 2047;
                    int s = m >> 10, h = (m >> 6) & 15, d = m & 63;
                    unsigned short* dst = (s == 0) ? qo : ((s == 1) ? ko : vo);
                    dst[((size_t)((bb << 4) + h) * T_SEQ + tt) * HD + d] = f2bf(val);
                } else {
                    o0[(size_t)n * 1024 + m] = val + bias[m];
                }
            }
        }
    }
}

// MFMA flash attention: grid (T/64, B*H), 256 threads (4 waves), wave owns 16 q-rows.
__global__ __launch_bounds__(256)
void attn_kernel(const unsigned short* __restrict__ qg, const unsigned short* __restrict__ kg,
                 const unsigned short* __restrict__ vg, const float* __restrict__ rel_bias,
                 unsigned short* __restrict__ y)
{
    __shared__ unsigned short Ks[2 * 64 * 32];      // [kstep][krow][32]  (gll16 layout)
    __shared__ unsigned short Vt[2 * 64 * 40];      // [kstep][hd][40] padded, kk xor-swizzled
    __shared__ unsigned short Pw[4 * 2 * 16 * 40];  // per-wave [kstep][qrow][40]
    __shared__ float bias_s[260];

    const int t = threadIdx.x;
    const int lane = t & 63, w = t >> 6;
    const int l15 = lane & 15, quad = lane >> 4;
    const int qt = blockIdx.x, bh = blockIdx.y;
    const int b = bh >> 4, h = bh & 15;
    const int q0 = qt << 6;
    const size_t base = (size_t)bh * T_SEQ * HD;

    for (int i = t; i < 257; i += 256) bias_s[i] = rel_bias[i * 16 + h];

    // Q fragments: wave w rows q0+w*16..+16, kept in registers for all K-tiles
    bf16x8 qf[2];
#pragma unroll
    for (int ks = 0; ks < 2; ++ks)
        qf[ks] = ldfrag(qg + base + (size_t)(q0 + w * 16 + l15) * HD + ks * 32 + quad * 8);

    float m_r[4], l_r[4];
#pragma unroll
    for (int r = 0; r < 4; ++r) { m_r[r] = -1e30f; l_r[r] = 0.f; }
    f32x4 Oacc[4] = {};

    const int ig = q0 + w * 16 + quad * 4;
    unsigned short* Pme = Pw + w * (2 * 16 * 40);
    const int kt0 = (qt > 8) ? (qt - 8) : 0;

    for (int kt = kt0; kt <= qt; ++kt) {
        // stage K tile (8 KB) via global_load_lds into [kstep][row][32]
        const char* kb = (const char*)(kg + base + (size_t)kt * 64 * HD);
#pragma unroll
        for (int i = 0; i < 2; ++i) {
            int c = w * 2 + i;
            int lin = c * 1024 + lane * 16;
            int ks = lin >> 12, rem = lin & 4095;
            int row = rem >> 6, colb = rem & 63;
            gll16(kb + row * 128 + ks * 64 + colb, (char*)Ks + c * 1024);
        }
        // stage V transposed: Vt[row>>5][col][ (row&31) ^ swz(col) ]
        {
            const unsigned short* vb = vg + base + (size_t)kt * 64 * HD;
#pragma unroll
            for (int i = 0; i < 2; ++i) {
                int g = t + i * 256;
                int row = g >> 3, cg = (g & 7) * 8;
                ushort8v vv = *reinterpret_cast<const ushort8v*>(vb + row * 64 + cg);
                int ksb = row >> 5, kk = row & 31;
#pragma unroll
                for (int j = 0; j < 8; ++j) {
                    int c = cg + j;
                    int kk2 = kk ^ (((c >> 3) & 3) << 3);
                    Vt[ksb * (64 * 40) + c * 40 + kk2] = vv[j];
                }
            }
        }
        __syncthreads();

        // S = Q K^T  (wave: 16x64 strip)
        f32x4 Sacc[4] = {};
#pragma unroll
        for (int ks = 0; ks < 2; ++ks)
#pragma unroll
            for (int ct = 0; ct < 4; ++ct) {
                bf16x8 kf = ldfrag(Ks + ks * 2048 + (ct * 16 + l15) * 32 + quad * 8);
                Sacc[ct] = __builtin_amdgcn_mfma_f32_16x16x32_bf16(qf[ks], kf, Sacc[ct], 0, 0, 0);
            }

        // mask + scale + rel-bias
        float sv[4][4];
#pragma unroll
        for (int ct = 0; ct < 4; ++ct) {
            int jg = (kt << 6) + ct * 16 + l15;
#pragma unroll
            for (int r = 0; r < 4; ++r) {
                int diff = ig + r - jg;
                sv[ct][r] = (diff < 0 || diff > 512) ? -1e30f
                          : Sacc[ct][r] * 0.125f + bias_s[(diff < 128 ? diff : 128) + 128];
            }
        }
        // row max across 64 cols: local over ct, then butterfly over the 16-lane col group
        float mx[4];
#pragma unroll
        for (int r = 0; r < 4; ++r)
            mx[r] = fmaxf(fmaxf(sv[0][r], sv[1][r]), fmaxf(sv[2][r], sv[3][r]));
#pragma unroll
        for (int off = 1; off < 16; off <<= 1)
#pragma unroll
            for (int r = 0; r < 4; ++r) mx[r] = fmaxf(mx[r], __shfl_xor(mx[r], off, 64));
        float alpha[4];
#pragma unroll
        for (int r = 0; r < 4; ++r) {
            float mn = fmaxf(m_r[r], mx[r]);
            alpha[r] = __expf(m_r[r] - mn);
            m_r[r] = mn;
        }
        // P = exp(S-m), row sums, write P to wave-private LDS in A-operand layout
        float ps[4] = {0.f, 0.f, 0.f, 0.f};
#pragma unroll
        for (int ct = 0; ct < 4; ++ct)
#pragma unroll
            for (int r = 0; r < 4; ++r) {
                float p = __expf(sv[ct][r] - m_r[r]);   // masked -> exp(-1e30)=0
                ps[r] += p;
                Pme[(ct >> 1) * (16 * 40) + (quad * 4 + r) * 40 + (ct & 1) * 16 + l15] = f2bf(p);
            }
#pragma unroll
        for (int off = 1; off < 16; off <<= 1)
#pragma unroll
            for (int r = 0; r < 4; ++r) ps[r] += __shfl_xor(ps[r], off, 64);
#pragma unroll
        for (int r = 0; r < 4; ++r) l_r[r] = l_r[r] * alpha[r] + ps[r];
        // O = O*alpha + P V
#pragma unroll
        for (int ct2 = 0; ct2 < 4; ++ct2)
#pragma unroll
            for (int r = 0; r < 4; ++r) Oacc[ct2][r] *= alpha[r];
#pragma unroll
        for (int ks = 0; ks < 2; ++ks) {
            bf16x8 pf = ldfrag(Pme + ks * (16 * 40) + l15 * 40 + quad * 8);
#pragma unroll
            for (int ct2 = 0; ct2 < 4; ++ct2) {
                int n = ct2 * 16 + l15;
                int quadv = quad ^ ((n >> 3) & 3);
                bf16x8 vf = ldfrag(Vt + ks * (64 * 40) + n * 40 + quadv * 8);
                Oacc[ct2] = __builtin_amdgcn_mfma_f32_16x16x32_bf16(pf, vf, Oacc[ct2], 0, 0, 0);
            }
        }
        __syncthreads();
    }

    // normalize + write bf16 (B,T,C) with head offset
    float inv[4];
#pragma unroll
    for (int r = 0; r < 4; ++r) inv[r] = 1.0f / l_r[r];
#pragma unroll
    for (int ct2 = 0; ct2 < 4; ++ct2)
#pragma unroll
        for (int r = 0; r < 4; ++r)
            y[((size_t)b * T_SEQ + q0 + w * 16 + quad * 4 + r) * 1024 + h * 64 + ct2 * 16 + l15]
                = f2bf(Oacc[ct2][r] * inv[r]);
}

extern "C" void kernel_launch(void* const* d_in, const int* in_sizes, int n_in,
                              void* d_out, int out_size, void* d_ws, size_t ws_size,
                              hipStream_t stream)
{
    (void)in_sizes; (void)n_in; (void)out_size; (void)ws_size;
    const float* x        = (const float*)d_in[0];
    const float* w_qkv    = (const float*)d_in[1];
    const float* w_proj   = (const float*)d_in[2];
    const float* b_proj   = (const float*)d_in[3];
    const float* rel_bias = (const float*)d_in[4];
    float* out = (float*)d_out;

    unsigned short* ws = (unsigned short*)d_ws;
    unsigned short* xb     = ws;                       // 4194304
    unsigned short* wqkvb  = xb + 4194304;             // 3145728
    unsigned short* wprojb = wqkvb + 3145728;          // 1048576
    unsigned short* qb     = wprojb + 1048576;         // 4194304
    unsigned short* kb     = qb + 4194304;             // 4194304
    unsigned short* vb     = kb + 4194304;             // 4194304
    unsigned short* yab    = vb + 4194304;             // 4194304

    cvt_kernel<<<2048, 256, 0, stream>>>(x, xb);
    cvt_kernel<<<1536, 256, 0, stream>>>(w_qkv, wqkvb);
    cvt_kernel<<<512, 256, 0, stream>>>(w_proj, wprojb);
    // qkv projection -> q,k,v bf16 (B,H,T,hd)
    gemm_kernel<0><<<dim3(24, 32), 256, 0, stream>>>(xb, wqkvb, nullptr, qb, kb, vb, nullptr);
    // local attention -> ya bf16 (B,T,C)
    attn_kernel<<<dim3(32, 32), 256, 0, stream>>>(qb, kb, vb, rel_bias, yab);
    // output projection + bias -> out fp32
    gemm_kernel<1><<<dim3(8, 32), 256, 0, stream>>>(yab, wprojb, out, nullptr, nullptr, nullptr, b_proj);
}

// Round 4
// 176.770 us; speedup vs baseline: 2.2022x; 1.0631x over previous
//
#include <hip/hip_runtime.h>

// B=2, T=2048, C=1024, H=16, hd=64, LOCAL_WINDOW=512, MAX_REL_DIST=128
#define T_SEQ 2048
#define HD 64

typedef float f32x4 __attribute__((ext_vector_type(4)));
typedef __bf16 bf16x8 __attribute__((ext_vector_type(8)));
typedef unsigned short ushort4v __attribute__((ext_vector_type(4)));
typedef unsigned short ushort8v __attribute__((ext_vector_type(8)));

__device__ __forceinline__ unsigned short f2bf(float f) {
    unsigned u = __builtin_bit_cast(unsigned, f);
    u += 0x7fffu + ((u >> 16) & 1u);
    return (unsigned short)(u >> 16);
}

__device__ __forceinline__ void gll16(const void* g, void* lds) {
    __builtin_amdgcn_global_load_lds(
        (const __attribute__((address_space(1))) unsigned int*)g,
        (__attribute__((address_space(3))) unsigned int*)lds, 16, 0, 0);
}

__device__ __forceinline__ bf16x8 ldfrag(const unsigned short* p) {
    return __builtin_bit_cast(bf16x8, *reinterpret_cast<const ushort8v*>(p));
}

// fused fp32->bf16 convert for x / w_qkv / w_proj (one launch)
__global__ __launch_bounds__(256)
void cvt_all_kernel(const float* __restrict__ x, const float* __restrict__ wq,
                    const float* __restrict__ wp, unsigned short* __restrict__ xb,
                    unsigned short* __restrict__ wqb, unsigned short* __restrict__ wpb)
{
    int bid = blockIdx.x;
    const float* s; unsigned short* d; int off;
    if (bid < 2048)      { s = x;  d = xb;  off = bid; }
    else if (bid < 3584) { s = wq; d = wqb; off = bid - 2048; }
    else                 { s = wp; d = wpb; off = bid - 3584; }
    int i = (off * 256 + threadIdx.x) * 8;
    f32x4 a = *reinterpret_cast<const f32x4*>(s + i);
    f32x4 b = *reinterpret_cast<const f32x4*>(s + i + 4);
    ushort8v o;
#pragma unroll
    for (int j = 0; j < 4; ++j) { o[j] = f2bf(a[j]); o[4 + j] = f2bf(b[j]); }
    *reinterpret_cast<ushort8v*>(d + i) = o;
}

// QKV GEMM: out[n][m] = sum_k A[n][k]*W[m][k], K=1024, 128x128 tile, 256 thr.
// Scatters q (pre-scaled by 0.125) and k as (B,H,T,hd); v TRANSPOSED as (B,H,hd,T).
__global__ __launch_bounds__(256)
void gemm_qkv_kernel(const unsigned short* __restrict__ A, const unsigned short* __restrict__ W,
                     unsigned short* __restrict__ qo, unsigned short* __restrict__ ko,
                     unsigned short* __restrict__ vo)
{
    constexpr int K = 1024;
    __shared__ unsigned short As[128 * 32];
    __shared__ unsigned short Bs[128 * 32];
    const int t = threadIdx.x;
    const int m0 = blockIdx.x * 128, n0 = blockIdx.y * 128;
    const int lane = t & 63, w = t >> 6;
    const int wy = w >> 1, wx = w & 1;
    const int l15 = lane & 15, quad = lane >> 4;

    f32x4 acc[4][4] = {};
    const char* Ab = (const char*)A;
    const char* Wb = (const char*)W;

    for (int kcl = 0; kcl < K; kcl += 32) {
#pragma unroll
        for (int i = 0; i < 2; ++i) {
            int c = w * 2 + i;                  // 1KB chunk 0..7
            int lin = c * 1024 + lane * 16;
            int row = lin >> 6;
            int kc = ((lin & 63) >> 4) ^ (row & 3);   // xor-swizzled 16B chunk
            gll16(Ab + ((size_t)(n0 + row) * K + kcl + kc * 8) * 2, (char*)As + c * 1024);
            gll16(Wb + ((size_t)(m0 + row) * K + kcl + kc * 8) * 2, (char*)Bs + c * 1024);
        }
        __syncthreads();
        bf16x8 af[4], bfr[4];
#pragma unroll
        for (int nt = 0; nt < 4; ++nt)
            af[nt] = ldfrag(As + (wy * 64 + nt * 16 + l15) * 32 + ((quad ^ (l15 & 3)) * 8));
#pragma unroll
        for (int mt = 0; mt < 4; ++mt)
            bfr[mt] = ldfrag(Bs + (wx * 64 + mt * 16 + l15) * 32 + ((quad ^ (l15 & 3)) * 8));
#pragma unroll
        for (int nt = 0; nt < 4; ++nt)
#pragma unroll
            for (int mt = 0; mt < 4; ++mt)
                acc[nt][mt] = __builtin_amdgcn_mfma_f32_16x16x32_bf16(af[nt], bfr[mt], acc[nt][mt], 0, 0, 0);
        __syncthreads();
    }

#pragma unroll
    for (int nt = 0; nt < 4; ++nt) {
#pragma unroll
        for (int mt = 0; mt < 4; ++mt) {
            const int m = m0 + wx * 64 + mt * 16 + l15;
            const int s = m >> 10, h = (m >> 6) & 15, d = m & 63;
#pragma unroll
            for (int r = 0; r < 4; ++r) {
                const int n = n0 + wy * 64 + nt * 16 + quad * 4 + r;
                const int bb = n >> 11, tt = n & 2047;
                float val = acc[nt][mt][r];
                if (s == 0)
                    qo[((size_t)((bb << 4) + h) * T_SEQ + tt) * HD + d] = f2bf(val * 0.125f);
                else if (s == 1)
                    ko[((size_t)((bb << 4) + h) * T_SEQ + tt) * HD + d] = f2bf(val);
                else
                    vo[((size_t)((bb << 4) + h) * HD + d) * T_SEQ + tt] = f2bf(val);
            }
        }
    }
}

// Proj GEMM: 512 threads (8 waves 4x2), 128x128 tile, out fp32 + bias.
__global__ __launch_bounds__(512, 4)
void gemm_proj_kernel(const unsigned short* __restrict__ A, const unsigned short* __restrict__ W,
                      float* __restrict__ o0, const float* __restrict__ bias)
{
    constexpr int K = 1024;
    __shared__ unsigned short As[128 * 32];
    __shared__ unsigned short Bs[128 * 32];
    const int t = threadIdx.x;
    const int m0 = blockIdx.x * 128, n0 = blockIdx.y * 128;
    const int lane = t & 63, w = t >> 6;
    const int wy = w >> 1, wx = w & 1;     // 4 (n) x 2 (m) waves; wave = 32n x 64m
    const int l15 = lane & 15, quad = lane >> 4;

    f32x4 acc[2][4] = {};
    const char* Ab = (const char*)A;
    const char* Wb = (const char*)W;
    const int srow = t >> 2;
    const int skc = (t & 3) ^ (srow & 3);

    for (int kcl = 0; kcl < K; kcl += 32) {
        gll16(Ab + ((size_t)(n0 + srow) * K + kcl + skc * 8) * 2, (char*)As + w * 1024);
        gll16(Wb + ((size_t)(m0 + srow) * K + kcl + skc * 8) * 2, (char*)Bs + w * 1024);
        __syncthreads();
        bf16x8 af[2], bfr[4];
#pragma unroll
        for (int nt = 0; nt < 2; ++nt)
            af[nt] = ldfrag(As + (wy * 32 + nt * 16 + l15) * 32 + ((quad ^ (l15 & 3)) * 8));
#pragma unroll
        for (int mt = 0; mt < 4; ++mt)
            bfr[mt] = ldfrag(Bs + (wx * 64 + mt * 16 + l15) * 32 + ((quad ^ (l15 & 3)) * 8));
#pragma unroll
        for (int nt = 0; nt < 2; ++nt)
#pragma unroll
            for (int mt = 0; mt < 4; ++mt)
                acc[nt][mt] = __builtin_amdgcn_mfma_f32_16x16x32_bf16(af[nt], bfr[mt], acc[nt][mt], 0, 0, 0);
        __syncthreads();
    }

#pragma unroll
    for (int nt = 0; nt < 2; ++nt)
#pragma unroll
        for (int mt = 0; mt < 4; ++mt) {
            const int m = m0 + wx * 64 + mt * 16 + l15;
            const float bm = bias[m];
#pragma unroll
            for (int r = 0; r < 4; ++r) {
                const int n = n0 + wy * 32 + nt * 16 + quad * 4 + r;
                o0[(size_t)n * 1024 + m] = acc[nt][mt][r] + bm;
            }
        }
}

// S^T-formulation MFMA flash attention.
// grid (T/128, B*H), 512 threads = 8 waves; wave owns 16 q rows (q = q0+w*16+l15 per lane).
// S^T = K Q^T (A=K, B=Q): lane holds 1 q-col, keys quad*4+r per 16-tile.
// O^T = V^T P (A=V^T from pre-transposed V, B=P via vectorized LDS round trip).
__global__ __launch_bounds__(512, 4)
void attn_kernel(const unsigned short* __restrict__ qg, const unsigned short* __restrict__ kg,
                 const unsigned short* __restrict__ vt, const float* __restrict__ rel_bias,
                 unsigned short* __restrict__ y)
{
    __shared__ unsigned short Ks[64 * 64];      // K tile [key][hd], 16B chunks xor-swizzled
    __shared__ unsigned short Vt[64 * 64];      // V^T tile [hd][key], same swizzle
    __shared__ unsigned short Pl[8 * 16 * 72];  // per-wave P [q(16)][key(64)+pad]
    __shared__ float bias_s[260];

    const int t = threadIdx.x;
    const int lane = t & 63, w = t >> 6;
    const int l15 = lane & 15, quad = lane >> 4;
    const int qt = blockIdx.x, bh = blockIdx.y;
    const int b = bh >> 4, h = bh & 15;
    const int q0 = qt << 7;
    const int qw0 = q0 + w * 16;
    const int q_row = qw0 + l15;
    const size_t base = (size_t)bh * T_SEQ * HD;   // same stride for k and v^t

    for (int i = t; i < 257; i += 512) bias_s[i] = rel_bias[i * 16 + h];

    // Q fragments (B operand: lane l15 = q, k = quad*8+j), scale pre-applied
    bf16x8 qf[2];
#pragma unroll
    for (int ks = 0; ks < 2; ++ks)
        qf[ks] = ldfrag(qg + base + (size_t)q_row * HD + ks * 32 + quad * 8);

    float m_r = -1e30f, l_r = 0.f;
    f32x4 Oacc[4] = {};                          // [mt over hd], col = q

    unsigned short* Pme = Pl + w * (16 * 72);
    // staging map: thread stages one 16B chunk of K and of V^T
    const int srow = t >> 3;                     // 0..63
    const int skc = (t & 7) ^ (srow & 7);        // global 16B chunk (xor-swizzled slot)

    const int kt0 = (qt * 2 > 8) ? (qt * 2 - 8) : 0;
    const int kt1 = qt * 2 + 1;

    for (int kt = kt0; kt <= kt1; ++kt) {
        gll16((const char*)(kg + base + (size_t)(kt * 64 + srow) * HD + skc * 8), (char*)Ks + w * 1024);
        gll16((const char*)(vt + base + (size_t)srow * T_SEQ + kt * 64 + skc * 8), (char*)Vt + w * 1024);
        __syncthreads();

        const int delta = qw0 - kt * 64;         // wave-uniform
        if (delta >= 0 && delta <= 560) {        // wave has work this tile
            // S^T = K Q^T
            f32x4 Sacc[4] = {};
#pragma unroll
            for (int ks = 0; ks < 2; ++ks)
#pragma unroll
                for (int ct = 0; ct < 4; ++ct) {
                    bf16x8 kf = ldfrag(Ks + (ct * 16 + l15) * 64 + (((ks * 4 + quad) ^ (l15 & 7)) * 8));
                    Sacc[ct] = __builtin_amdgcn_mfma_f32_16x16x32_bf16(kf, qf[ks], Sacc[ct], 0, 0, 0);
                }

            float sv[4][4];
            if (delta >= 192 && delta <= 496) {
                // fast path: no mask possible, bias == bias[256] for all pairs
                const float bC = bias_s[256];
#pragma unroll
                for (int ct = 0; ct < 4; ++ct)
#pragma unroll
                    for (int r = 0; r < 4; ++r) sv[ct][r] = Sacc[ct][r] + bC;
            } else {
#pragma unroll
                for (int ct = 0; ct < 4; ++ct)
#pragma unroll
                    for (int r = 0; r < 4; ++r) {
                        int diff = q_row - (kt * 64 + ct * 16 + quad * 4 + r);
                        float bb = bias_s[(diff < 128 ? diff : 128) + 128];
                        float s = Sacc[ct][r] + bb;
                        sv[ct][r] = (diff < 0 || diff > 512) ? -1e30f : s;
                    }
            }

            // online softmax (per-lane scalar state; reduce across quad groups)
            float mx = -1e30f;
#pragma unroll
            for (int ct = 0; ct < 4; ++ct)
#pragma unroll
                for (int r = 0; r < 4; ++r) mx = fmaxf(mx, sv[ct][r]);
            mx = fmaxf(mx, __shfl_xor(mx, 16, 64));
            mx = fmaxf(mx, __shfl_xor(mx, 32, 64));
            float mn = fmaxf(m_r, mx);
            float alpha = __expf(m_r - mn);
            m_r = mn;
            float ps = 0.f;
            float p[4][4];
#pragma unroll
            for (int ct = 0; ct < 4; ++ct)
#pragma unroll
                for (int r = 0; r < 4; ++r) { p[ct][r] = __expf(sv[ct][r] - mn); ps += p[ct][r]; }
            ps += __shfl_xor(ps, 16, 64);
            ps += __shfl_xor(ps, 32, 64);
            l_r = l_r * alpha + ps;

            // P -> wave-private LDS (vectorized b64: lane's 4 keys are contiguous)
#pragma unroll
            for (int ct = 0; ct < 4; ++ct) {
                ushort4v pw;
#pragma unroll
                for (int j = 0; j < 4; ++j) pw[j] = f2bf(p[ct][j]);
                *reinterpret_cast<ushort4v*>(Pme + l15 * 72 + ct * 16 + quad * 4) = pw;
            }
#pragma unroll
            for (int mt = 0; mt < 4; ++mt) Oacc[mt] *= alpha;
#pragma unroll
            for (int ks = 0; ks < 2; ++ks) {
                bf16x8 pf = ldfrag(Pme + l15 * 72 + ks * 32 + quad * 8);
#pragma unroll
                for (int mt = 0; mt < 4; ++mt) {
                    bf16x8 vf = ldfrag(Vt + (mt * 16 + l15) * 64 + (((ks * 4 + quad) ^ (l15 & 7)) * 8));
                    Oacc[mt] = __builtin_amdgcn_mfma_f32_16x16x32_bf16(vf, pf, Oacc[mt], 0, 0, 0);
                }
            }
        }
        __syncthreads();
    }

    // normalize + write: lane's 16 outputs are one q row, contiguous per mt (b64 stores)
    const float inv = 1.0f / l_r;
    unsigned short* yp = y + ((size_t)b * T_SEQ + q_row) * 1024 + h * 64;
#pragma unroll
    for (int mt = 0; mt < 4; ++mt) {
        ushort4v o;
#pragma unroll
        for (int j = 0; j < 4; ++j) o[j] = f2bf(Oacc[mt][j] * inv);
        *reinterpret_cast<ushort4v*>(yp + mt * 16 + quad * 4) = o;
    }
}

extern "C" void kernel_launch(void* const* d_in, const int* in_sizes, int n_in,
                              void* d_out, int out_size, void* d_ws, size_t ws_size,
                              hipStream_t stream)
{
    (void)in_sizes; (void)n_in; (void)out_size; (void)ws_size;
    const float* x        = (const float*)d_in[0];
    const float* w_qkv    = (const float*)d_in[1];
    const float* w_proj   = (const float*)d_in[2];
    const float* b_proj   = (const float*)d_in[3];
    const float* rel_bias = (const float*)d_in[4];
    float* out = (float*)d_out;

    unsigned short* ws = (unsigned short*)d_ws;
    unsigned short* xb     = ws;                       // 4194304
    unsigned short* wqkvb  = xb + 4194304;             // 3145728
    unsigned short* wprojb = wqkvb + 3145728;          // 1048576
    unsigned short* qb     = wprojb + 1048576;         // 4194304 (B,H,T,hd), pre-scaled
    unsigned short* kb     = qb + 4194304;             // 4194304 (B,H,T,hd)
    unsigned short* vtb    = kb + 4194304;             // 4194304 (B,H,hd,T)  TRANSPOSED
    unsigned short* yab    = vtb + 4194304;            // 4194304 (B,T,C)

    cvt_all_kernel<<<4096, 256, 0, stream>>>(x, w_qkv, w_proj, xb, wqkvb, wprojb);
    gemm_qkv_kernel<<<dim3(24, 32), 256, 0, stream>>>(xb, wqkvb, qb, kb, vtb);
    attn_kernel<<<dim3(16, 32), 512, 0, stream>>>(qb, kb, vtb, rel_bias, yab);
    gemm_proj_kernel<<<dim3(8, 32), 512, 0, stream>>>(yab, wprojb, out, b_proj);
}